// Round 1
// baseline (3056.807 us; speedup 1.0000x reference)
//
#include <hip/hip_runtime.h>
#include <math.h>

#define B_D 64
#define B_H 512

// tanh via hardware exp; clamp avoids inf/inf NaN, tanh saturated anyway
__device__ __forceinline__ float fast_tanh(float x) {
    x = fminf(fmaxf(x, -15.0f), 15.0f);
    float e = __expf(2.0f * x);
    return (e - 1.0f) / (e + 1.0f);
}

__device__ __forceinline__ float dot64(const float* a, const float* b) {
    float s0 = 0.f, s1 = 0.f, s2 = 0.f, s3 = 0.f;
#pragma unroll
    for (int d = 0; d < B_D; d += 4) {
        s0 += a[d] * b[d];
        s1 += a[d + 1] * b[d + 1];
        s2 += a[d + 2] * b[d + 2];
        s3 += a[d + 3] * b[d + 3];
    }
    return (s0 + s1) + (s2 + s3);
}

// o = mobius_add(sx*x, sy*y); safe when o aliases x or y (elementwise after scalars)
__device__ __forceinline__ void mobius(const float* x, const float* y, float* o,
                                       float sx, float sy) {
    float xy0 = 0, xy1 = 0, xy2 = 0, xy3 = 0;
    float x20 = 0, x21 = 0, x22 = 0, x23 = 0;
    float y20 = 0, y21 = 0, y22 = 0, y23 = 0;
#pragma unroll
    for (int d = 0; d < B_D; d += 4) {
        float a0 = sx * x[d], a1 = sx * x[d + 1], a2 = sx * x[d + 2], a3 = sx * x[d + 3];
        float b0 = sy * y[d], b1 = sy * y[d + 1], b2 = sy * y[d + 2], b3 = sy * y[d + 3];
        xy0 += a0 * b0; xy1 += a1 * b1; xy2 += a2 * b2; xy3 += a3 * b3;
        x20 += a0 * a0; x21 += a1 * a1; x22 += a2 * a2; x23 += a3 * a3;
        y20 += b0 * b0; y21 += b1 * b1; y22 += b2 * b2; y23 += b3 * b3;
    }
    float xy = (xy0 + xy1) + (xy2 + xy3);
    float x2 = (x20 + x21) + (x22 + x23);
    float y2 = (y20 + y21) + (y22 + y23);
    float nx = 1.0f + 2.0f * xy + y2;
    float ny = 1.0f - x2;
    float inv = 1.0f / fmaxf(1.0f + 2.0f * xy + x2 * y2, 1e-5f);
#pragma unroll
    for (int d = 0; d < B_D; ++d)
        o[d] = (nx * (sx * x[d]) + ny * (sy * y[d])) * inv;
}

// ph[d] += sum_h (1-tanh^2(q.W1col_h + b1_h)) * (-0.05*W2_h) * W1[d][h]
// sW1T is [H][D] f32 in LDS; all lanes read same row -> LDS broadcast.
// Fused fwd-dot + bwd-axpy so each row is read once per eval.
__device__ __forceinline__ void grad_update(const float* q, float* ph,
                                            const float* sW1T, const float* sb1,
                                            const float* sw2) {
    for (int h = 0; h < B_H; ++h) {
        const float* row = sW1T + (h << 6);
        float a0 = 0.f, a1 = 0.f, a2 = 0.f, a3 = 0.f;
#pragma unroll
        for (int d = 0; d < B_D; d += 4) {
            a0 += q[d] * row[d];
            a1 += q[d + 1] * row[d + 1];
            a2 += q[d + 2] * row[d + 2];
            a3 += q[d + 3] * row[d + 3];
        }
        float acc = sb1[h] + ((a0 + a1) + (a2 + a3));
        float t = fast_tanh(acc);
        float u = (1.0f - t * t) * sw2[h];
#pragma unroll
        for (int d = 0; d < B_D; ++d) ph[d] += u * row[d];
    }
}

__global__ __launch_bounds__(512, 2)
void leapfrog_kernel(const float* __restrict__ gq, const float* __restrict__ gp,
                     const float* __restrict__ gW1, const float* __restrict__ gb1,
                     const float* __restrict__ gW2, float* __restrict__ out, int B) {
    __shared__ float sW1T[B_H * B_D];  // 128 KB: W1 transposed, [h][d]
    __shared__ float sb1[B_H];
    __shared__ float sw2[B_H];         // -0.5*DT*W2 pre-folded

    for (int i = threadIdx.x; i < B_D * B_H; i += 512) {
        int d = i >> 9;            // W1 is [64][512] row-major
        int h = i & (B_H - 1);
        sW1T[(h << 6) + d] = gW1[i];
    }
    if (threadIdx.x < B_H) {
        sb1[threadIdx.x] = gb1[threadIdx.x];
        sw2[threadIdx.x] = -0.05f * gW2[threadIdx.x];
    }
    __syncthreads();

    int pt = blockIdx.x * 512 + threadIdx.x;
    if (pt >= B) return;

    float q[B_D], p[B_D], qn[B_D];
    {
        const float4* q4 = reinterpret_cast<const float4*>(gq + (size_t)pt * B_D);
        const float4* p4 = reinterpret_cast<const float4*>(gp + (size_t)pt * B_D);
#pragma unroll
        for (int d = 0; d < B_D / 4; ++d) {
            float4 a = q4[d]; float4 b = p4[d];
            q[4 * d] = a.x; q[4 * d + 1] = a.y; q[4 * d + 2] = a.z; q[4 * d + 3] = a.w;
            p[4 * d] = b.x; p[4 * d + 1] = b.y; p[4 * d + 2] = b.z; p[4 * d + 3] = b.w;
        }
    }

#pragma unroll 1
    for (int step = 0; step < 4; ++step) {
        // ---- first half-kick: p_half = p - 0.05*gHq ----
        float qq = dot64(q, q);
        float pp = dot64(p, p);
        float s = fmaxf(1.0f - qq, 1e-5f);          // clipped 1-||q||^2
        float c0 = 0.025f * pp * s;                 // -0.05 * (-0.5*pp*s)
#pragma unroll
        for (int d = 0; d < B_D; ++d) p[d] += c0 * q[d];
        grad_update(q, p, sW1T, sb1, sw2);          // p now = p_half

        // ---- drift: q_new = exp_map(q, DT * p_half * s^2/4) ----
        float fac = 0.025f * s * s;                 // DT * s^2 / 4
        float ph2 = dot64(p, p);
        float vn = fmaxf(fac * sqrtf(ph2), 1e-15f);
        float th = fast_tanh(vn / s);               // tanh(0.5*lam*vn), lam=2/s
        float sc = th * fac / vn;                   // second = sc * p_half
        {
            float qdp = dot64(q, p);
            float xy = sc * qdp;
            float y2 = sc * sc * ph2;
            float nx = 1.0f + 2.0f * xy + y2;
            float ny = 1.0f - qq;                   // raw ||q||^2 (unclipped)
            float inv = 1.0f / fmaxf(1.0f + 2.0f * xy + qq * y2, 1e-5f);
#pragma unroll
            for (int d = 0; d < B_D; ++d)
                qn[d] = (nx * q[d] + ny * sc * p[d]) * inv;
        }
        float qq2 = dot64(qn, qn);
        float s2 = fmaxf(1.0f - qq2, 1e-5f);

        // ---- parallel transport p_half from q to qn ----
        // gyr[qn, -q] p_half = (-(qn (+) -q)) (+) (qn (+) ((-q) (+) p_half))
        mobius(q, p, p, -1.0f, 1.0f);   // p = m1 = (-q) (+) p_half
        mobius(qn, p, p, 1.0f, 1.0f);   // p = m2 = qn (+) m1
        mobius(qn, q, q, 1.0f, -1.0f);  // q = m3 = qn (+) (-q)   (q dead after)
        mobius(q, p, p, -1.0f, 1.0f);   // p = (-m3) (+) m2
        float ratio = s2 / s;           // lambda_q / lambda_qn
#pragma unroll
        for (int d = 0; d < B_D; ++d) p[d] *= ratio;   // p = p_t

        // ---- second half-kick at qn ----
        float pp2 = dot64(p, p);
        float c2 = 0.025f * pp2 * s2;
#pragma unroll
        for (int d = 0; d < B_D; ++d) p[d] += c2 * qn[d];
        grad_update(qn, p, sW1T, sb1, sw2);         // p = p_new

#pragma unroll
        for (int d = 0; d < B_D; ++d) q[d] = qn[d];
    }

    // output: concat(q, p) flat, f32
    float* oq = out + (size_t)pt * B_D;
    float* op = out + (size_t)B * B_D + (size_t)pt * B_D;
#pragma unroll
    for (int d = 0; d < B_D; ++d) oq[d] = q[d];
#pragma unroll
    for (int d = 0; d < B_D; ++d) op[d] = p[d];
}

extern "C" void kernel_launch(void* const* d_in, const int* in_sizes, int n_in,
                              void* d_out, int out_size, void* d_ws, size_t ws_size,
                              hipStream_t stream) {
    const float* gq  = (const float*)d_in[0];
    const float* gp  = (const float*)d_in[1];
    const float* gW1 = (const float*)d_in[2];
    const float* gb1 = (const float*)d_in[3];
    const float* gW2 = (const float*)d_in[4];
    // d_in[5] = b2 : does not affect gradients -> unused
    float* out = (float*)d_out;

    int B = in_sizes[0] / B_D;
    int blocks = (B + 511) / 512;
    leapfrog_kernel<<<blocks, 512, 0, stream>>>(gq, gp, gW1, gb1, gW2, out, B);
}

// Round 5
// 2992.629 us; speedup vs baseline: 1.0214x; 1.0214x over previous
//
#include <hip/hip_runtime.h>
#include <math.h>

#define B_D 64
#define B_H 512
#define TPB 512
#define HD 32   // components per thread (half of D)

// tanh via hardware exp; clamp avoids inf/inf NaN, tanh saturated anyway
__device__ __forceinline__ float fast_tanh(float x) {
    x = fminf(fmaxf(x, -15.0f), 15.0f);
    float e = __expf(2.0f * x);
    return (e - 1.0f) / (e + 1.0f);
}

// sum over the lane pair (lane ^ 1) -> full-D dot from half-D partials
__device__ __forceinline__ float psum(float v) {
    return v + __shfl_xor(v, 1);
}

__device__ __forceinline__ float dot32(const float* a, const float* b) {
    float s0 = 0.f, s1 = 0.f, s2 = 0.f, s3 = 0.f;
#pragma unroll
    for (int d = 0; d < HD; d += 4) {
        s0 += a[d] * b[d];
        s1 += a[d + 1] * b[d + 1];
        s2 += a[d + 2] * b[d + 2];
        s3 += a[d + 3] * b[d + 3];
    }
    return (s0 + s1) + (s2 + s3);
}

// o = mobius_add(sx*x, sy*y) on this thread's half; dots reduced over lane pair.
// Safe when o aliases x or y.
__device__ __forceinline__ void mobius_h(const float* x, const float* y, float* o,
                                         float sx, float sy) {
    float xy0 = 0, xy1 = 0, x20 = 0, x21 = 0, y20 = 0, y21 = 0;
#pragma unroll
    for (int d = 0; d < HD; d += 2) {
        float a0 = sx * x[d], a1 = sx * x[d + 1];
        float b0 = sy * y[d], b1 = sy * y[d + 1];
        xy0 += a0 * b0; xy1 += a1 * b1;
        x20 += a0 * a0; x21 += a1 * a1;
        y20 += b0 * b0; y21 += b1 * b1;
    }
    float xy = psum(xy0 + xy1);
    float x2 = psum(x20 + x21);
    float y2 = psum(y20 + y21);
    float nx = 1.0f + 2.0f * xy + y2;
    float ny = 1.0f - x2;
    float inv = 1.0f / fmaxf(1.0f + 2.0f * xy + x2 * y2, 1e-5f);
#pragma unroll
    for (int d = 0; d < HD; ++d)
        o[d] = (nx * (sx * x[d]) + ny * (sy * y[d])) * inv;
}

// ph[d] += sum_h (1 - tanh^2(q.W1col_h + b1_h)) * (-0.05*W2_h) * W1half[d][h]
// Row-half register-cached: read once from LDS, used by dot and axpy.
__device__ __forceinline__ void grad_update(const float* qh, float* ph,
                                            const float* sW1T, const float2* sbw,
                                            int off) {
#pragma unroll 2
    for (int h = 0; h < B_H; ++h) {
        const float4* r4 = reinterpret_cast<const float4*>(sW1T + (h << 6) + off);
        float row[HD];
#pragma unroll
        for (int i = 0; i < HD / 4; ++i) {
            float4 v = r4[i];
            row[4 * i] = v.x; row[4 * i + 1] = v.y;
            row[4 * i + 2] = v.z; row[4 * i + 3] = v.w;
        }
        float a = dot32(qh, row);
        float2 bw = sbw[h];
        float acc = bw.x + psum(a);
        float t = fast_tanh(acc);
        float u = (1.0f - t * t) * bw.y;
#pragma unroll
        for (int d = 0; d < HD; ++d) ph[d] += u * row[d];
    }
}

__global__ __launch_bounds__(TPB, 2)
void leapfrog_kernel(const float* __restrict__ gq, const float* __restrict__ gp,
                     const float* __restrict__ gW1, const float* __restrict__ gb1,
                     const float* __restrict__ gW2, float* __restrict__ out, int B) {
    __shared__ float sW1T[B_H * B_D];   // 128 KB: W1 transposed, [h][d]
    __shared__ float2 sbw[B_H];         // {b1[h], -0.05*W2[h]}

    for (int i = threadIdx.x; i < B_D * B_H; i += TPB) {
        int d = i >> 9;                 // W1 is [64][512] row-major
        int h = i & (B_H - 1);
        sW1T[(h << 6) + d] = gW1[i];
    }
    if (threadIdx.x < B_H) {
        sbw[threadIdx.x] = make_float2(gb1[threadIdx.x], -0.05f * gW2[threadIdx.x]);
    }
    __syncthreads();

    int tid = blockIdx.x * TPB + threadIdx.x;
    int pt = tid >> 1;                  // lane pair per point
    int off = (tid & 1) * HD;           // this thread's component range
    if (pt >= B) return;

    float q[HD], p[HD], qn[HD];
    {
        const float4* q4 = reinterpret_cast<const float4*>(gq + (size_t)pt * B_D + off);
        const float4* p4 = reinterpret_cast<const float4*>(gp + (size_t)pt * B_D + off);
#pragma unroll
        for (int d = 0; d < HD / 4; ++d) {
            float4 a = q4[d]; float4 b = p4[d];
            q[4 * d] = a.x; q[4 * d + 1] = a.y; q[4 * d + 2] = a.z; q[4 * d + 3] = a.w;
            p[4 * d] = b.x; p[4 * d + 1] = b.y; p[4 * d + 2] = b.z; p[4 * d + 3] = b.w;
        }
    }

#pragma unroll 1
    for (int step = 0; step < 4; ++step) {
        // ---- first half-kick: p_half = p - 0.05*gHq ----
        float qq = psum(dot32(q, q));
        float pp = psum(dot32(p, p));
        float s = fmaxf(1.0f - qq, 1e-5f);          // clipped 1-||q||^2
        float c0 = 0.025f * pp * s;                 // -0.05 * dT/dq coefficient
#pragma unroll
        for (int d = 0; d < HD; ++d) p[d] += c0 * q[d];
        grad_update(q, p, sW1T, sbw, off);          // p now = p_half

        // ---- drift: q_new = exp_map(q, DT * p_half * s^2/4) ----
        float fac = 0.025f * s * s;                 // DT * s^2 / 4
        float ph2 = psum(dot32(p, p));
        float vn = fmaxf(fac * sqrtf(ph2), 1e-15f);
        float th = fast_tanh(vn / s);               // tanh(0.5*lam*vn), lam=2/s
        float sc = th * fac / vn;                   // second = sc * p_half
        {
            float qdp = psum(dot32(q, p));
            float xy = sc * qdp;
            float y2 = sc * sc * ph2;
            float nx = 1.0f + 2.0f * xy + y2;
            float ny = 1.0f - qq;                   // raw ||q||^2 (unclipped)
            float inv = 1.0f / fmaxf(1.0f + 2.0f * xy + qq * y2, 1e-5f);
#pragma unroll
            for (int d = 0; d < HD; ++d)
                qn[d] = (nx * q[d] + ny * sc * p[d]) * inv;
        }
        float qq2 = psum(dot32(qn, qn));
        float s2 = fmaxf(1.0f - qq2, 1e-5f);

        // ---- parallel transport p_half from q to qn ----
        // gyr[qn, -q] p_half = (-(qn (+) -q)) (+) (qn (+) ((-q) (+) p_half))
        mobius_h(q, p, p, -1.0f, 1.0f);   // p = m1 = (-q) (+) p_half
        mobius_h(qn, p, p, 1.0f, 1.0f);   // p = m2 = qn (+) m1
        mobius_h(qn, q, q, 1.0f, -1.0f);  // q = m3 = qn (+) (-q)   (q dead after)
        mobius_h(q, p, p, -1.0f, 1.0f);   // p = (-m3) (+) m2
        float ratio = s2 / s;             // lambda_q / lambda_qn
#pragma unroll
        for (int d = 0; d < HD; ++d) p[d] *= ratio;   // p = p_t

        // ---- second half-kick at qn ----
        float pp2 = psum(dot32(p, p));
        float c2 = 0.025f * pp2 * s2;
#pragma unroll
        for (int d = 0; d < HD; ++d) p[d] += c2 * qn[d];
        grad_update(qn, p, sW1T, sbw, off);         // p = p_new

#pragma unroll
        for (int d = 0; d < HD; ++d) q[d] = qn[d];
    }

    // output: concat(q, p) flat, f32
    float* oq = out + (size_t)pt * B_D + off;
    float* op = out + (size_t)B * B_D + (size_t)pt * B_D + off;
#pragma unroll
    for (int d = 0; d < HD / 4; ++d) {
        reinterpret_cast<float4*>(oq)[d] =
            make_float4(q[4 * d], q[4 * d + 1], q[4 * d + 2], q[4 * d + 3]);
        reinterpret_cast<float4*>(op)[d] =
            make_float4(p[4 * d], p[4 * d + 1], p[4 * d + 2], p[4 * d + 3]);
    }
}

extern "C" void kernel_launch(void* const* d_in, const int* in_sizes, int n_in,
                              void* d_out, int out_size, void* d_ws, size_t ws_size,
                              hipStream_t stream) {
    const float* gq  = (const float*)d_in[0];
    const float* gp  = (const float*)d_in[1];
    const float* gW1 = (const float*)d_in[2];
    const float* gb1 = (const float*)d_in[3];
    const float* gW2 = (const float*)d_in[4];
    // d_in[5] = b2 : does not affect gradients -> unused
    float* out = (float*)d_out;

    int B = in_sizes[0] / B_D;
    long long threads = 2LL * B;
    int blocks = (int)((threads + TPB - 1) / TPB);
    leapfrog_kernel<<<blocks, TPB, 0, stream>>>(gq, gp, gW1, gb1, gW2, out, B);
}